// Round 9
// baseline (744.521 us; speedup 1.0000x reference)
//
#include <hip/hip_runtime.h>
#include <math.h>

#define EPSV 1e-5f
#define SCALE_W 0.0441941738241592f   /* 1/sqrt(512) */
#define GAIN_R 1.4142135623730951f    /* sqrt(2) */

typedef __attribute__((ext_vector_type(8))) short bf16x8;
typedef __attribute__((ext_vector_type(4))) float f32x4;
typedef __attribute__((ext_vector_type(4))) unsigned int u32x4;

static __device__ __forceinline__ unsigned short f2bf(float f) {
  union { float f; unsigned int u; } v; v.f = f;
  unsigned int r = v.u + 0x7FFFu + ((v.u >> 16) & 1u);   // RNE
  return (unsigned short)(r >> 16);
}

#define GLD_LDS16(gsrc, ldst)                                                                      \
  __builtin_amdgcn_global_load_lds((const __attribute__((address_space(1))) unsigned int*)(gsrc),  \
                                   (__attribute__((address_space(3))) unsigned int*)(ldst), 16, 0, 0)

// lgkm-only barrier: does NOT drain vmcnt -> in-flight loads/gload_lds survive
#define LBAR() do {                                          \
  asm volatile("s_waitcnt lgkmcnt(0)" ::: "memory");         \
  __builtin_amdgcn_sched_barrier(0);                         \
  __builtin_amdgcn_s_barrier();                              \
  __builtin_amdgcn_sched_barrier(0);                         \
} while (0)

#define VMCNT(N) do {                                        \
  asm volatile("s_waitcnt vmcnt(" #N ")" ::: "memory");      \
  __builtin_amdgcn_sched_barrier(0);                         \
} while (0)

// keep value live without cost (rule #17: ablation-via-skip DCEs upstream ops)
#define KEEP(v) asm volatile("" :: "v"(v))

// ---------------- pre-kernel: b = expmap0(bias), y2 = ||b||^2 ----------------
__global__ void bias_expmap_k(const float* __restrict__ bias, float* __restrict__ bexp,
                              float* __restrict__ y2out) {
  __shared__ float part[8];
  int t = threadIdx.x;
  float bv = bias[t];
  float s = bv * bv;
  s += __shfl_xor(s, 1);  s += __shfl_xor(s, 2);  s += __shfl_xor(s, 4);
  s += __shfl_xor(s, 8);  s += __shfl_xor(s, 16); s += __shfl_xor(s, 32);
  if ((t & 63) == 0) part[t >> 6] = s;
  __syncthreads();
  float tot = 0.f;
#pragma unroll
  for (int i = 0; i < 8; ++i) tot += part[i];
  float un = fmaxf(sqrtf(tot), EPSV);
  float th = tanhf(un);
  bexp[t] = th * bv / un;
  if (t == 0) *y2out = th * th;
}

// ---------------- pre-kernel: pack weight -> bf16 fragments, SCALE baked ----
__global__ void pack_weight_k(const float* __restrict__ w, unsigned short* __restrict__ wsB) {
  int e = blockIdx.x * 256 + threadIdx.x;   // 0..262143
  int o = e >> 9;          // output col (row of W)
  int k = e & 511;
  int ks = k >> 5, kk = k & 31;
  int lgr = kk >> 3, j = kk & 7;
  int colhi = o >> 4, l15 = o & 15;
  int dst = ((ks * 32 + colhi) * 64 + lgr * 16 + l15) * 8 + j;
  wsB[dst] = f2bf(w[e] * SCALE_W);
}

// ---------------- main fused kernel (R8 structure, template-ablated) ----------------
// V=0 full | V=1 no B-stage | V=2 no A-stage | V=3 no epilogue (raw stores) | V=4 no MFMA
#define RB 80
#define ABUF 5120        /* 64*80 */
#define BOFF 10240
#define BBUF 32768
#define SCR 75776
#define SMEMSZ 80896

template<int V>
__global__ __launch_bounds__(256, 2)
void hyp_main_k(const float* __restrict__ x, const unsigned short* __restrict__ wsB,
                const float* __restrict__ bexp, const float* __restrict__ y2p,
                float* __restrict__ out, int tilesPerBlk) {
  extern __shared__ char smem[];
  const int tid  = threadIdx.x;
  const int lane = tid & 63;
  const int wave = tid >> 6;       // 0..3 : col group (128 cols each)
  const int l15  = lane & 15;
  const int lgr  = lane >> 4;      // 0..3
  const int srow = tid >> 2;       // stage row 0..63
  const int sq   = tid & 3;        // k-subgroup (8 floats)

  float* xn2      = (float*)(smem + SCR);          // [64] (reused as tml)
  float* pS2      = (float*)(smem + SCR + 256);    // [64][4] (reused as pN2)
  float* pSB      = (float*)(smem + SCR + 1280);   // [64][4]
  float* g12      = (float*)(smem + SCR + 2304);   // [64][2]
  float* bexp_lds = (float*)(smem + SCR + 2816);   // [512]
  float* y2l      = (float*)(smem + SCR + 4864);   // [1]

  f32x4 acc[4][8];
#pragma unroll
  for (int mf = 0; mf < 4; ++mf)
#pragma unroll
    for (int nf = 0; nf < 8; ++nf) acc[mf][nf] = f32x4{0.f, 0.f, 0.f, 0.f};

  const long base = (long)blockIdx.x * tilesPerBlk;
  const int U = tilesPerBlk * 16;
  float xss = 0.f;
  f32x4 stA, stB;

  // ---- prologue (identical in all variants) ----
  {
    float2 bc = *(const float2*)(bexp + tid * 2);
    *(float2*)(bexp_lds + tid * 2) = bc;
    if (tid == 0) *y2l = *y2p;
    const float* p = x + (size_t)(base * 64 + srow) * 512 + sq * 8;
    f32x4 a = *(const f32x4*)p;
    f32x4 b = *(const f32x4*)(p + 4);
    xss += a[0]*a[0] + a[1]*a[1] + a[2]*a[2] + a[3]*a[3];
    xss += b[0]*b[0] + b[1]*b[1] + b[2]*b[2] + b[3]*b[3];
    u32x4 pk;
    pk[0] = (unsigned int)f2bf(a[0]) | ((unsigned int)f2bf(a[1]) << 16);
    pk[1] = (unsigned int)f2bf(a[2]) | ((unsigned int)f2bf(a[3]) << 16);
    pk[2] = (unsigned int)f2bf(b[0]) | ((unsigned int)f2bf(b[1]) << 16);
    pk[3] = (unsigned int)f2bf(b[2]) | ((unsigned int)f2bf(b[3]) << 16);
    *(u32x4*)(smem + srow * RB + sq * 16) = pk;   // A buf 0
#pragma unroll
    for (int i = 0; i < 8; ++i)
      GLD_LDS16((const char*)wsB + (wave * 8 + i) * 1024 + lane * 16,
                smem + BOFF + (wave * 8 + i) * 1024);
  }
  LBAR();

#pragma unroll 1
  for (int t = 0; t < U; ++t) {
    const int cur = t & 1, nxt = cur ^ 1;
    const bool epi = ((t & 15) == 15);
    const bool postepi = (t > 0 && (t & 15) == 0);

    // 1. issue A(t+1) loads (2)  [skipped in V2]
    if constexpr (V != 2) {
      const int gu = (t + 1 < U) ? t + 1 : U - 1;
      const float* p = x + (size_t)((base + (gu >> 4)) * 64 + srow) * 512 + (gu & 15) * 32 + sq * 8;
      stA = *(const f32x4*)p;
      stB = *(const f32x4*)(p + 4);
    }
    // 2. issue B(t+1) gloads (8) -> B buf nxt  [skipped in V1]
    if constexpr (V != 1) {
      const char* bs = (const char*)wsB + (size_t)((t + 1) & 15) * 32768;
      char* bd = smem + BOFF + nxt * BBUF;
#pragma unroll
      for (int i = 0; i < 8; ++i)
        GLD_LDS16(bs + (wave * 8 + i) * 1024 + lane * 16, bd + (wave * 8 + i) * 1024);
    }
    // 3. drain current step's B only (per-variant ledger)
    if constexpr (V == 1) {
      // queue: [A2] (+st32 after epi) -- nothing needed for MFMA; no drain
    } else if constexpr (V == 2) {
      if (postepi) { VMCNT(40); } else { VMCNT(8); }
    } else {
      if (postepi) { VMCNT(42); } else { VMCNT(10); }
    }

    // 4. fragments + MFMA (swapped operands)
    {
      const char* ab = smem + cur * ABUF + l15 * RB + lgr * 16;
      const char* bb = smem + BOFF + cur * BBUF + (wave * 8) * 1024 + lane * 16;
      bf16x8 xf[4], wf[8];
#pragma unroll
      for (int mf = 0; mf < 4; ++mf) xf[mf] = *(const bf16x8*)(ab + mf * (16 * RB));
#pragma unroll
      for (int nf = 0; nf < 8; ++nf) wf[nf] = *(const bf16x8*)(bb + nf * 1024);
      if constexpr (V == 4) {
        asm volatile("s_waitcnt lgkmcnt(0)" ::: "memory");
        __builtin_amdgcn_sched_barrier(0);
#pragma unroll
        for (int mf = 0; mf < 4; ++mf) KEEP(xf[mf]);
#pragma unroll
        for (int nf = 0; nf < 8; ++nf) KEEP(wf[nf]);
      } else {
        __builtin_amdgcn_s_setprio(1);
#pragma unroll
        for (int mf = 0; mf < 4; ++mf)
#pragma unroll
          for (int nf = 0; nf < 8; ++nf)
            acc[mf][nf] = __builtin_amdgcn_mfma_f32_16x16x32_bf16(wf[nf], xf[mf], acc[mf][nf], 0, 0, 0);
        __builtin_amdgcn_s_setprio(0);
      }
    }

    // 5. per-tile epilogue
    if (epi) {
      const long trow = (base + (t >> 4)) * 64;
      if constexpr (V == 3) {
        // raw stores: same traffic/addresses, no hyperbolic math, no LBARs
#pragma unroll
        for (int mf = 0; mf < 4; ++mf)
#pragma unroll
          for (int nf = 0; nf < 8; ++nf) {
            *(f32x4*)(out + (size_t)(trow + mf * 16 + l15) * 512 +
                      wave * 128 + nf * 16 + lgr * 4) = acc[mf][nf];
            acc[mf][nf] = f32x4{0.f, 0.f, 0.f, 0.f};
          }
        xss = 0.f;
      } else {
        float xs = xss;
        xs += __shfl_xor(xs, 1); xs += __shfl_xor(xs, 2);
        if (sq == 0) xn2[srow] = xs;
        xss = 0.f;

        f32x4 bvv[8];
#pragma unroll
        for (int nf = 0; nf < 8; ++nf)
          bvv[nf] = *(const f32x4*)(bexp_lds + wave * 128 + nf * 16 + lgr * 4);

        float s2[4], sb[4];
#pragma unroll
        for (int mf = 0; mf < 4; ++mf) {
          s2[mf] = 0.f; sb[mf] = 0.f;
#pragma unroll
          for (int nf = 0; nf < 8; ++nf)
#pragma unroll
            for (int j = 0; j < 4; ++j) {
              float v = acc[mf][nf][j];
              s2[mf] += v * v;
              sb[mf] += v * bvv[nf][j];
            }
          s2[mf] += __shfl_xor(s2[mf], 16); s2[mf] += __shfl_xor(s2[mf], 32);
          sb[mf] += __shfl_xor(sb[mf], 16); sb[mf] += __shfl_xor(sb[mf], 32);
        }
        if (lane < 16) {
#pragma unroll
          for (int mf = 0; mf < 4; ++mf) {
            pS2[(mf * 16 + l15) * 4 + wave] = s2[mf];
            pSB[(mf * 16 + l15) * 4 + wave] = sb[mf];
          }
        }
        LBAR();

        if (tid < 64) {
          int r = tid;
          float S2 = 0.f, SB = 0.f;
#pragma unroll
          for (int i = 0; i < 4; ++i) { S2 += pS2[r * 4 + i]; SB += pSB[r * 4 + i]; }
          float y2s = *y2l;
          float xn  = fmaxf(sqrtf(xn2[r]), EPSV);
          float mxn = fmaxf(sqrtf(S2), EPSV);
          float f = tanhf((mxn / xn) * atanhf(fminf(xn, 1.f - EPSV))) / mxn;  // mv = f*mx
          float xy = f * SB;
          float x2 = f * f * S2;
          float den = 1.f + 2.f * xy + x2 * y2s + EPSV;
          float g1 = (1.f + 2.f * xy + y2s) * f / den;   // coeff on mx
          float g2 = (1.f - x2) / den;                   // coeff on b
          float n1sq = g1 * g1 * S2 + 2.f * g1 * g2 * SB + g2 * g2 * y2s;
          float n1 = fmaxf(sqrtf(fmaxf(n1sq, 0.f)), EPSV);
          if (n1 > 0.999f) { float sc = 0.999f / n1; g1 *= sc; g2 *= sc; }   // project()
          g12[r * 2] = g1; g12[r * 2 + 1] = g2;
        }
        LBAR();

        float n2p[4];
#pragma unroll
        for (int mf = 0; mf < 4; ++mf) {
          float g1 = g12[(mf * 16 + l15) * 2], g2 = g12[(mf * 16 + l15) * 2 + 1];
          n2p[mf] = 0.f;
#pragma unroll
          for (int nf = 0; nf < 8; ++nf)
#pragma unroll
            for (int j = 0; j < 4; ++j) {
              float v = g1 * acc[mf][nf][j] + g2 * bvv[nf][j];
              v = v > 0.f ? v : 0.2f * v;
              acc[mf][nf][j] = v;
              n2p[mf] += v * v;
            }
          n2p[mf] += __shfl_xor(n2p[mf], 16); n2p[mf] += __shfl_xor(n2p[mf], 32);
        }
        if (lane < 16) {
#pragma unroll
          for (int mf = 0; mf < 4; ++mf) pS2[(mf * 16 + l15) * 4 + wave] = n2p[mf];  // pN2
        }
        LBAR();

        if (tid < 64) {
          int r = tid;
          float sn = 0.f;
#pragma unroll
          for (int i = 0; i < 4; ++i) sn += pS2[r * 4 + i];
          float n2 = fmaxf(sqrtf(sn), EPSV);
          xn2[r] = tanhf(GAIN_R * atanhf(fminf(n2, 1.f - EPSV))) / n2;  // tml
        }
        LBAR();

#pragma unroll
        for (int mf = 0; mf < 4; ++mf) {
          float tm = xn2[mf * 16 + l15];
#pragma unroll
          for (int nf = 0; nf < 8; ++nf) {
            f32x4 o = acc[mf][nf];
            o[0] *= tm; o[1] *= tm; o[2] *= tm; o[3] *= tm;
            *(f32x4*)(out + (size_t)(trow + mf * 16 + l15) * 512 +
                      wave * 128 + nf * 16 + lgr * 4) = o;
            acc[mf][nf] = f32x4{0.f, 0.f, 0.f, 0.f};
          }
        }
      }
    }

    // 6. drain A(t+1) only, then pack + ds_write  [skipped in V2]
    if constexpr (V == 2) {
      // no A path
    } else {
      if constexpr (V == 1) {
        if (epi) { VMCNT(32); } else { VMCNT(0); }
      } else {
        if (epi) { VMCNT(40); } else { VMCNT(8); }
      }
      f32x4 a = stA, b = stB;
      xss += a[0]*a[0] + a[1]*a[1] + a[2]*a[2] + a[3]*a[3];
      xss += b[0]*b[0] + b[1]*b[1] + b[2]*b[2] + b[3]*b[3];
      u32x4 pk;
      pk[0] = (unsigned int)f2bf(a[0]) | ((unsigned int)f2bf(a[1]) << 16);
      pk[1] = (unsigned int)f2bf(a[2]) | ((unsigned int)f2bf(a[3]) << 16);
      pk[2] = (unsigned int)f2bf(b[0]) | ((unsigned int)f2bf(b[1]) << 16);
      pk[3] = (unsigned int)f2bf(b[2]) | ((unsigned int)f2bf(b[3]) << 16);
      *(u32x4*)(smem + nxt * ABUF + srow * RB + sq * 16) = pk;
    }
    // 7.
    LBAR();
  }
}

extern "C" void kernel_launch(void* const* d_in, const int* in_sizes, int n_in,
                              void* d_out, int out_size, void* d_ws, size_t ws_size,
                              hipStream_t stream) {
  const float* x    = (const float*)d_in[0];
  const float* w    = (const float*)d_in[1];
  const float* bias = (const float*)d_in[2];
  float* out = (float*)d_out;

  unsigned short* wsB = (unsigned short*)d_ws;                 // 524288 B
  float* bexp = (float*)((char*)d_ws + 524288);                // 2048 B
  float* y2p  = (float*)((char*)d_ws + 524288 + 2048);         // 4 B

  bias_expmap_k<<<dim3(1), dim3(512), 0, stream>>>(bias, bexp, y2p);
  pack_weight_k<<<dim3(1024), dim3(256), 0, stream>>>(w, wsB);

  const int nrows  = in_sizes[0] / 512;      // 131072
  const int ntiles = nrows / 64;             // 2048
  const int nblk   = 512;                    // 2 blocks/CU
  const int tpb    = ntiles / nblk;          // 4

  // ablation dispatches (write d_out, later overwritten by V0)
  hyp_main_k<1><<<dim3(nblk), dim3(256), SMEMSZ, stream>>>(x, wsB, bexp, y2p, out, tpb);
  hyp_main_k<2><<<dim3(nblk), dim3(256), SMEMSZ, stream>>>(x, wsB, bexp, y2p, out, tpb);
  hyp_main_k<3><<<dim3(nblk), dim3(256), SMEMSZ, stream>>>(x, wsB, bexp, y2p, out, tpb);
  hyp_main_k<4><<<dim3(nblk), dim3(256), SMEMSZ, stream>>>(x, wsB, bexp, y2p, out, tpb);
  // the real kernel, last: produces the validated output
  hyp_main_k<0><<<dim3(nblk), dim3(256), SMEMSZ, stream>>>(x, wsB, bexp, y2p, out, tpb);
}

// Round 10
// 184.520 us; speedup vs baseline: 4.0349x; 4.0349x over previous
//
#include <hip/hip_runtime.h>
#include <math.h>

#define EPSV 1e-5f
#define SCALE_W 0.0441941738241592f   /* 1/sqrt(512) */
#define GAIN_R 1.4142135623730951f    /* sqrt(2) */

typedef __attribute__((ext_vector_type(8))) short bf16x8;
typedef __attribute__((ext_vector_type(4))) float f32x4;
typedef __attribute__((ext_vector_type(4))) unsigned int u32x4;

static __device__ __forceinline__ unsigned short f2bf(float f) {
  union { float f; unsigned int u; } v; v.f = f;
  unsigned int r = v.u + 0x7FFFu + ((v.u >> 16) & 1u);   // RNE
  return (unsigned short)(r >> 16);
}

#define GLD_LDS16(gsrc, ldst)                                                                      \
  __builtin_amdgcn_global_load_lds((const __attribute__((address_space(1))) unsigned int*)(gsrc),  \
                                   (__attribute__((address_space(3))) unsigned int*)(ldst), 16, 0, 0)

// lgkm-only barrier: does NOT drain vmcnt -> in-flight loads/gload_lds survive
#define LBAR() do {                                          \
  asm volatile("s_waitcnt lgkmcnt(0)" ::: "memory");         \
  __builtin_amdgcn_sched_barrier(0);                         \
  __builtin_amdgcn_s_barrier();                              \
  __builtin_amdgcn_sched_barrier(0);                         \
} while (0)

#define VMCNT(N) do {                                        \
  asm volatile("s_waitcnt vmcnt(" #N ")" ::: "memory");      \
  __builtin_amdgcn_sched_barrier(0);                         \
} while (0)

// ---------------- pre-kernel: b = expmap0(bias), y2 = ||b||^2 ----------------
__global__ void bias_expmap_k(const float* __restrict__ bias, float* __restrict__ bexp,
                              float* __restrict__ y2out) {
  __shared__ float part[8];
  int t = threadIdx.x;
  float bv = bias[t];
  float s = bv * bv;
  s += __shfl_xor(s, 1);  s += __shfl_xor(s, 2);  s += __shfl_xor(s, 4);
  s += __shfl_xor(s, 8);  s += __shfl_xor(s, 16); s += __shfl_xor(s, 32);
  if ((t & 63) == 0) part[t >> 6] = s;
  __syncthreads();
  float tot = 0.f;
#pragma unroll
  for (int i = 0; i < 8; ++i) tot += part[i];
  float un = fmaxf(sqrtf(tot), EPSV);
  float th = tanhf(un);
  bexp[t] = th * bv / un;
  if (t == 0) *y2out = th * th;
}

// ---------------- pre-kernel: pack weight -> bf16 fragments, SCALE baked ----
// chunk = (ks*32 + colhi): 64 lanes x 16B; lane (lgr*16+l15) holds
// W[col=colhi*16+l15][k=ks*32+lgr*8+j], j=0..7.
__global__ void pack_weight_k(const float* __restrict__ w, unsigned short* __restrict__ wsB) {
  int e = blockIdx.x * 256 + threadIdx.x;   // 0..262143
  int o = e >> 9;          // output col (row of W)
  int k = e & 511;
  int ks = k >> 5, kk = k & 31;
  int lgr = kk >> 3, j = kk & 7;
  int colhi = o >> 4, l15 = o & 15;
  int dst = ((ks * 32 + colhi) * 64 + lgr * 16 + l15) * 8 + j;
  wsB[dst] = f2bf(w[e] * SCALE_W);
}

// ---------------- main fused kernel ----------------
// 512 thr / 8 waves, BM=128, BN=512, BK=32. Wave tile 128x64 (mf=8, nf=4).
// A: reg-staged NT fp32->bf16, dbuf [128 rows][80 B]. B: gload_lds dbuf 2x32KB
// (4 gloads/thread/step). One lgkm barrier pair per K-step; counted vmcnt.
#define RB 80
#define ABUF 10240       /* 128*80 */
#define BOFF 20480
#define BBUF 32768
#define SCR 86016
#define SMEMSZ 97824

__global__ __launch_bounds__(512, 2)
void hyp_main_k(const float* __restrict__ x, const unsigned short* __restrict__ wsB,
                const float* __restrict__ bexp, const float* __restrict__ y2p,
                float* __restrict__ out, int tilesPerBlk) {
  extern __shared__ char smem[];
  const int tid  = threadIdx.x;
  const int lane = tid & 63;
  const int wave = tid >> 6;       // 0..7 : col group (64 cols each)
  const int l15  = lane & 15;
  const int lgr  = lane >> 4;      // 0..3
  const int srow = tid >> 2;       // stage row 0..127
  const int sq   = tid & 3;        // k-subgroup (8 floats)

  float* xn2      = (float*)(smem + SCR);          // [128] (reused as tml)
  float* pS2      = (float*)(smem + SCR + 512);    // [128][8] (reused as pN2)
  float* pSB      = (float*)(smem + SCR + 4608);   // [128][8]
  float* g12      = (float*)(smem + SCR + 8704);   // [128][2]
  float* bexp_lds = (float*)(smem + SCR + 9728);   // [512]
  float* y2l      = (float*)(smem + SCR + 11776);  // [1]

  f32x4 acc[8][4];
#pragma unroll
  for (int mf = 0; mf < 8; ++mf)
#pragma unroll
    for (int nf = 0; nf < 4; ++nf) acc[mf][nf] = f32x4{0.f, 0.f, 0.f, 0.f};

  const long base = (long)blockIdx.x * tilesPerBlk;
  const int U = tilesPerBlk * 16;
  float xss = 0.f;
  f32x4 stA, stB;

  // ---- prologue ----
  {
    bexp_lds[tid] = bexp[tid];
    if (tid == 0) *y2l = *y2p;
    // A(0): row base*128+srow, k = sq*8..sq*8+7
    const float* p = x + (size_t)(base * 128 + srow) * 512 + sq * 8;
    f32x4 a = __builtin_nontemporal_load((const f32x4*)p);
    f32x4 b = __builtin_nontemporal_load((const f32x4*)(p + 4));
    xss += a[0]*a[0] + a[1]*a[1] + a[2]*a[2] + a[3]*a[3];
    xss += b[0]*b[0] + b[1]*b[1] + b[2]*b[2] + b[3]*b[3];
    u32x4 pk;
    pk[0] = (unsigned int)f2bf(a[0]) | ((unsigned int)f2bf(a[1]) << 16);
    pk[1] = (unsigned int)f2bf(a[2]) | ((unsigned int)f2bf(a[3]) << 16);
    pk[2] = (unsigned int)f2bf(b[0]) | ((unsigned int)f2bf(b[1]) << 16);
    pk[3] = (unsigned int)f2bf(b[2]) | ((unsigned int)f2bf(b[3]) << 16);
    *(u32x4*)(smem + srow * RB + sq * 16) = pk;   // A buf 0
    // B(0) -> B buf 0: 4 chunks per thread (wave w stages its own chunks w*4..w*4+3)
#pragma unroll
    for (int i = 0; i < 4; ++i)
      GLD_LDS16((const char*)wsB + (wave * 4 + i) * 1024 + lane * 16,
                smem + BOFF + (wave * 4 + i) * 1024);
  }
  LBAR();

#pragma unroll 1
  for (int t = 0; t < U; ++t) {
    const int cur = t & 1, nxt = cur ^ 1;
    const bool epi = ((t & 15) == 15);
    const bool postepi = (t > 0 && (t & 15) == 0);

    // 1. issue A(t+1) loads (2, nontemporal: protect wsB's L2 residency)
    {
      const int gu = (t + 1 < U) ? t + 1 : U - 1;
      const float* p = x + (size_t)((base + (gu >> 4)) * 128 + srow) * 512 + (gu & 15) * 32 + sq * 8;
      stA = __builtin_nontemporal_load((const f32x4*)p);
      stB = __builtin_nontemporal_load((const f32x4*)(p + 4));
    }
    // 2. issue B(t+1) gloads (4) -> B buf nxt
    {
      const char* bs = (const char*)wsB + (size_t)((t + 1) & 15) * 32768;
      char* bd = smem + BOFF + nxt * BBUF;
#pragma unroll
      for (int i = 0; i < 4; ++i)
        GLD_LDS16(bs + (wave * 4 + i) * 1024 + lane * 16, bd + (wave * 4 + i) * 1024);
    }
    // 3. drain B(t) only. queue: [B(t)4, A2, B4] (+ST32 ahead on postepi)
    if (postepi) { VMCNT(38); } else { VMCNT(6); }
    LBAR();

    // 4. fragments + MFMA (swapped operands: store row = mf*16+l15)
    {
      const char* ab = smem + cur * ABUF + l15 * RB + lgr * 16;
      const char* bb = smem + BOFF + cur * BBUF + (wave * 4) * 1024 + lane * 16;
      bf16x8 xf[8], wf[4];
#pragma unroll
      for (int mf = 0; mf < 8; ++mf) xf[mf] = *(const bf16x8*)(ab + mf * (16 * RB));
#pragma unroll
      for (int nf = 0; nf < 4; ++nf) wf[nf] = *(const bf16x8*)(bb + nf * 1024);
      __builtin_amdgcn_s_setprio(1);
#pragma unroll
      for (int mf = 0; mf < 8; ++mf)
#pragma unroll
        for (int nf = 0; nf < 4; ++nf)
          acc[mf][nf] = __builtin_amdgcn_mfma_f32_16x16x32_bf16(wf[nf], xf[mf], acc[mf][nf], 0, 0, 0);
      __builtin_amdgcn_s_setprio(0);
    }

    // 5. fused hyperbolic epilogue
    if (epi) {
      const long trow = (base + (t >> 4)) * 128;

      float xs = xss;
      xs += __shfl_xor(xs, 1); xs += __shfl_xor(xs, 2);
      if (sq == 0) xn2[srow] = xs;
      xss = 0.f;

      f32x4 bvv[4];
#pragma unroll
      for (int nf = 0; nf < 4; ++nf)
        bvv[nf] = *(const f32x4*)(bexp_lds + wave * 64 + nf * 16 + lgr * 4);

      float s2[8], sb[8];
#pragma unroll
      for (int mf = 0; mf < 8; ++mf) {
        s2[mf] = 0.f; sb[mf] = 0.f;
#pragma unroll
        for (int nf = 0; nf < 4; ++nf)
#pragma unroll
          for (int j = 0; j < 4; ++j) {
            float v = acc[mf][nf][j];
            s2[mf] += v * v;
            sb[mf] += v * bvv[nf][j];
          }
        s2[mf] += __shfl_xor(s2[mf], 16); s2[mf] += __shfl_xor(s2[mf], 32);
        sb[mf] += __shfl_xor(sb[mf], 16); sb[mf] += __shfl_xor(sb[mf], 32);
      }
      if (lane < 16) {
#pragma unroll
        for (int mf = 0; mf < 8; ++mf) {
          pS2[(mf * 16 + l15) * 8 + wave] = s2[mf];
          pSB[(mf * 16 + l15) * 8 + wave] = sb[mf];
        }
      }
      LBAR();

      if (tid < 128) {
        int r = tid;
        float S2 = 0.f, SB = 0.f;
#pragma unroll
        for (int i = 0; i < 8; ++i) { S2 += pS2[r * 8 + i]; SB += pSB[r * 8 + i]; }
        float y2s = *y2l;
        float xn  = fmaxf(sqrtf(xn2[r]), EPSV);
        float mxn = fmaxf(sqrtf(S2), EPSV);
        float f = tanhf((mxn / xn) * atanhf(fminf(xn, 1.f - EPSV))) / mxn;  // mv = f*mx
        float xy = f * SB;
        float x2 = f * f * S2;
        float den = 1.f + 2.f * xy + x2 * y2s + EPSV;
        float g1 = (1.f + 2.f * xy + y2s) * f / den;   // coeff on mx
        float g2 = (1.f - x2) / den;                   // coeff on b
        float n1sq = g1 * g1 * S2 + 2.f * g1 * g2 * SB + g2 * g2 * y2s;
        float n1 = fmaxf(sqrtf(fmaxf(n1sq, 0.f)), EPSV);
        if (n1 > 0.999f) { float sc = 0.999f / n1; g1 *= sc; g2 *= sc; }   // project()
        g12[r * 2] = g1; g12[r * 2 + 1] = g2;
      }
      LBAR();

      float n2p[8];
#pragma unroll
      for (int mf = 0; mf < 8; ++mf) {
        float g1 = g12[(mf * 16 + l15) * 2], g2 = g12[(mf * 16 + l15) * 2 + 1];
        n2p[mf] = 0.f;
#pragma unroll
        for (int nf = 0; nf < 4; ++nf)
#pragma unroll
          for (int j = 0; j < 4; ++j) {
            float v = g1 * acc[mf][nf][j] + g2 * bvv[nf][j];
            v = v > 0.f ? v : 0.2f * v;
            acc[mf][nf][j] = v;
            n2p[mf] += v * v;
          }
        n2p[mf] += __shfl_xor(n2p[mf], 16); n2p[mf] += __shfl_xor(n2p[mf], 32);
      }
      if (lane < 16) {
#pragma unroll
        for (int mf = 0; mf < 8; ++mf) pS2[(mf * 16 + l15) * 8 + wave] = n2p[mf];  // pN2
      }
      LBAR();

      if (tid < 128) {
        int r = tid;
        float sn = 0.f;
#pragma unroll
        for (int i = 0; i < 8; ++i) sn += pS2[r * 8 + i];
        float n2 = fmaxf(sqrtf(sn), EPSV);
        xn2[r] = tanhf(GAIN_R * atanhf(fminf(n2, 1.f - EPSV))) / n2;  // tml
      }
      LBAR();

      // stores (32 x 16B per thread; counted in the vmcnt ledger)
#pragma unroll
      for (int mf = 0; mf < 8; ++mf) {
        float tm = xn2[mf * 16 + l15];
#pragma unroll
        for (int nf = 0; nf < 4; ++nf) {
          f32x4 o = acc[mf][nf];
          o[0] *= tm; o[1] *= tm; o[2] *= tm; o[3] *= tm;
          *(f32x4*)(out + (size_t)(trow + mf * 16 + l15) * 512 +
                    wave * 64 + nf * 16 + lgr * 4) = o;
          acc[mf][nf] = f32x4{0.f, 0.f, 0.f, 0.f};
        }
      }
    }

    // 6. drain A(t+1) only (epi: 32 stores sit between A and B in the queue)
    if (epi) { VMCNT(36); } else { VMCNT(4); }

    // pack + ds_write A(t+1) -> A buf nxt
    {
      f32x4 a = stA, b = stB;
      xss += a[0]*a[0] + a[1]*a[1] + a[2]*a[2] + a[3]*a[3];
      xss += b[0]*b[0] + b[1]*b[1] + b[2]*b[2] + b[3]*b[3];
      u32x4 pk;
      pk[0] = (unsigned int)f2bf(a[0]) | ((unsigned int)f2bf(a[1]) << 16);
      pk[1] = (unsigned int)f2bf(a[2]) | ((unsigned int)f2bf(a[3]) << 16);
      pk[2] = (unsigned int)f2bf(b[0]) | ((unsigned int)f2bf(b[1]) << 16);
      pk[3] = (unsigned int)f2bf(b[2]) | ((unsigned int)f2bf(b[3]) << 16);
      *(u32x4*)(smem + nxt * ABUF + srow * RB + sq * 16) = pk;
    }
    // 7.
    LBAR();
  }
}

extern "C" void kernel_launch(void* const* d_in, const int* in_sizes, int n_in,
                              void* d_out, int out_size, void* d_ws, size_t ws_size,
                              hipStream_t stream) {
  const float* x    = (const float*)d_in[0];
  const float* w    = (const float*)d_in[1];
  const float* bias = (const float*)d_in[2];
  float* out = (float*)d_out;

  unsigned short* wsB = (unsigned short*)d_ws;                 // 524288 B
  float* bexp = (float*)((char*)d_ws + 524288);                // 2048 B
  float* y2p  = (float*)((char*)d_ws + 524288 + 2048);         // 4 B

  bias_expmap_k<<<dim3(1), dim3(512), 0, stream>>>(bias, bexp, y2p);
  pack_weight_k<<<dim3(1024), dim3(256), 0, stream>>>(w, wsB);

  const int nrows  = in_sizes[0] / 512;      // 131072
  const int ntiles = nrows / 128;            // 1024
  const int nblk   = 256;                    // 1 block/CU, persistent
  const int tpb    = ntiles / nblk;          // 4
  hyp_main_k<<<dim3(nblk), dim3(512), SMEMSZ, stream>>>(x, wsB, bexp, y2p, out, tpb);
}